// Round 5
// baseline (357.799 us; speedup 1.0000x reference)
//
#include <hip/hip_runtime.h>

// Problem constants (fixed by reference setup_inputs).
#define N 32
#define T 64
#define C 256
#define L 64
#define CHUNKS 32              // blocks per n; each block owns 2 consecutive t-rows
#define GRID_BLOCKS (CHUNKS * N)   // 1024 blocks: 4/CU needed, >=4/CU guaranteed by launch_bounds
#define PARTIAL_ELEMS (CHUNKS * N * L)   // 65536 floats = 256 KiB

// Fused kernel with homemade grid barrier (device-scope atomic + acquire spin).
// Phase 1: partial[chunk][n][l] = sum_c of this block's 2 t-rows q[n,t,c,l]*k[t,n,c].
//          Row t0's q values (64 KiB/block = 16 float4/thread) are RETAINED in
//          registers across the barrier; row t1 is streamed.
// Barrier: all 1024 blocks co-resident (launch_bounds(256,4) -> VGPR<=128 ->
//          4 blocks/CU capacity x 256 CUs = 1024).
// Phase 2: redundant per-block softmax over the 32 partials (L2-hot), then
//          out[t0] from retained registers (zero q traffic) and out[t1] by
//          re-streaming (L3-hot from phase 1).
__global__ __launch_bounds__(256, 4) void fused_kernel(
    const float* __restrict__ q, const float* __restrict__ k,
    float* __restrict__ partial, unsigned int* __restrict__ bar,
    float* __restrict__ out) {
  const int chunk = blockIdx.x;   // 0..31
  const int n     = blockIdx.y;   // 0..31
  const int t0    = chunk * 2;
  const int tid   = threadIdx.x;
  const int lane  = tid & 63;
  const int wave  = tid >> 6;      // 0..3
  const int sub   = lane >> 4;     // 0..3
  const int lq    = lane & 15;     // l-group: l = 4*lq..4*lq+3
  const int g     = wave * 4 + sub; // quarter-wave id 0..15 -> c = g, g+16, ...

  __shared__ float ks[2 * C];      // k rows t0,t0+1 (2 KiB)
  __shared__ float sdata[4 * L];   // cross-wave reduce (1 KiB), reused in phase 2
  __shared__ float probs[L];

  ks[tid]       = k[t0 * (N * C) + n * C + tid];
  ks[tid + C]   = k[(t0 + 1) * (N * C) + n * C + tid];
  __syncthreads();

  const float* q0 = q + ((size_t)n * T + t0) * (C * L);
  const float* q1 = q0 + (size_t)(C * L);

  // ---- Phase 1a: row t0, retained in registers (64 VGPRs payload) ----
  float4 hold[16];
  #pragma unroll
  for (int j = 0; j < 16; ++j) {
    const int c = g + j * 16;
    hold[j] = *reinterpret_cast<const float4*>(q0 + (size_t)c * L + lq * 4);
  }
  float4 acc = make_float4(0.f, 0.f, 0.f, 0.f);
  #pragma unroll
  for (int j = 0; j < 16; ++j) {
    const float kv = ks[g + j * 16];
    acc.x = fmaf(hold[j].x, kv, acc.x);
    acc.y = fmaf(hold[j].y, kv, acc.y);
    acc.z = fmaf(hold[j].z, kv, acc.z);
    acc.w = fmaf(hold[j].w, kv, acc.w);
  }
  // ---- Phase 1b: row t1, streamed ----
  #pragma unroll 4
  for (int c = g; c < C; c += 16) {
    const float4 qv = *reinterpret_cast<const float4*>(q1 + (size_t)c * L + lq * 4);
    const float kv = ks[C + c];
    acc.x = fmaf(qv.x, kv, acc.x);
    acc.y = fmaf(qv.y, kv, acc.y);
    acc.z = fmaf(qv.z, kv, acc.z);
    acc.w = fmaf(qv.w, kv, acc.w);
  }

  // Quarter-wave accumulators hold same l-groups, different c: sum across subs.
  acc.x += __shfl_xor(acc.x, 16); acc.y += __shfl_xor(acc.y, 16);
  acc.z += __shfl_xor(acc.z, 16); acc.w += __shfl_xor(acc.w, 16);
  acc.x += __shfl_xor(acc.x, 32); acc.y += __shfl_xor(acc.y, 32);
  acc.z += __shfl_xor(acc.z, 32); acc.w += __shfl_xor(acc.w, 32);

  if (lane < 16) {
    sdata[wave * L + lq * 4 + 0] = acc.x;
    sdata[wave * L + lq * 4 + 1] = acc.y;
    sdata[wave * L + lq * 4 + 2] = acc.z;
    sdata[wave * L + lq * 4 + 3] = acc.w;
  }
  __syncthreads();
  if (tid < L) {
    const float s = sdata[tid] + sdata[L + tid] + sdata[2 * L + tid] + sdata[3 * L + tid];
    partial[(size_t)chunk * (N * L) + n * L + tid] = s;
  }
  __syncthreads();   // partial writes happen-before tid0's fence below

  // ---- Grid barrier (canonical release/acquire pattern) ----
  if (tid == 0) {
    __threadfence();                       // publish this block's partial row
    atomicAdd(bar, 1u);                    // device-scope by default
    while (__hip_atomic_load(bar, __ATOMIC_ACQUIRE, __HIP_MEMORY_SCOPE_AGENT)
           < (unsigned)GRID_BLOCKS) {
      __builtin_amdgcn_s_sleep(8);
    }
    __threadfence();
  }
  __syncthreads();

  // ---- Phase 2: softmax over l (redundant per block; 8 KiB L2-hot reads) ----
  {
    float s = 0.f;   // wave w sums partial chunks [8w, 8w+8), lane = l
    #pragma unroll
    for (int b = wave * 8; b < wave * 8 + 8; ++b)
      s += partial[(size_t)b * (N * L) + n * L + lane];
    sdata[wave * L + lane] = s;
  }
  __syncthreads();
  if (tid < L) {   // exactly wave 0
    float s = sdata[tid] + sdata[L + tid] + sdata[2 * L + tid] + sdata[3 * L + tid];
    float m = s;
    #pragma unroll
    for (int off = 32; off > 0; off >>= 1) m = fmaxf(m, __shfl_xor(m, off));
    const float e = __expf(s - m);
    float sum = e;
    #pragma unroll
    for (int off = 32; off > 0; off >>= 1) sum += __shfl_xor(sum, off);
    probs[tid] = e / sum;
  }
  __syncthreads();

  const float4 pv = *reinterpret_cast<const float4*>(&probs[lq * 4]);

  // ---- Phase 2a: row t0 from retained registers (zero q traffic) ----
  #pragma unroll
  for (int j = 0; j < 16; ++j) {
    float d = hold[j].x * pv.x + hold[j].y * pv.y + hold[j].z * pv.z + hold[j].w * pv.w;
    d += __shfl_xor(d, 1);
    d += __shfl_xor(d, 2);
    d += __shfl_xor(d, 4);
    d += __shfl_xor(d, 8);
    if (lq == 0)
      __builtin_nontemporal_store(d, &out[t0 * (N * C) + n * C + (g + j * 16)]);
  }
  // ---- Phase 2b: row t1 re-streamed (L3-hot) ----
  #pragma unroll 4
  for (int c = g; c < C; c += 16) {
    const float4 qv = *reinterpret_cast<const float4*>(q1 + (size_t)c * L + lq * 4);
    float d = qv.x * pv.x + qv.y * pv.y + qv.z * pv.z + qv.w * pv.w;
    d += __shfl_xor(d, 1);
    d += __shfl_xor(d, 2);
    d += __shfl_xor(d, 4);
    d += __shfl_xor(d, 8);
    if (lq == 0)
      __builtin_nontemporal_store(d, &out[(t0 + 1) * (N * C) + n * C + c]);
  }
}

extern "C" void kernel_launch(void* const* d_in, const int* in_sizes, int n_in,
                              void* d_out, int out_size, void* d_ws, size_t ws_size,
                              hipStream_t stream) {
  const float* q = (const float*)d_in[0];   // query: (32,64,256,64) fp32
  const float* k = (const float*)d_in[1];   // key:   (64,32,256)    fp32
  float* out = (float*)d_out;               // out:   (64,32,256)    fp32
  float* partial = (float*)d_ws;            // [32][32][64] fp32 = 256 KiB
  unsigned int* bar = (unsigned int*)((char*)d_ws + (size_t)PARTIAL_ELEMS * 4);

  // Zero the barrier counter (ws is poisoned 0xAA before every launch).
  hipMemsetAsync((void*)bar, 0, sizeof(unsigned int), stream);

  dim3 grid(CHUNKS, N);                     // 1024 blocks x 256 threads
  fused_kernel<<<grid, 256, 0, stream>>>(q, k, partial, bar, out);
}

// Round 6
// 211.980 us; speedup vs baseline: 1.6879x; 1.6879x over previous
//
#include <hip/hip_runtime.h>

// Problem constants (fixed by reference setup_inputs).
#define N 32
#define T 64
#define C 256
#define L 64
#define BLK_PER_N 64                   // == T: each block owns exactly one (n,t)

// Kernel 1: partial[t][n][l] = sum_c q[n,t,c,l] * k[t,n,c]
// Block = 256 threads = 4 waves = 16 quarter-waves of 16 lanes. Block (t,n) stages
// its contiguous k-row k[t,n,0:256] (1 KiB) into LDS once, then streams its 64 KiB
// q chunk: quarter-wave g handles c = g, g+16, ...; lane lq loads the float4
// q[n,t,c,4lq..4lq+3] (coalesced 16B/lane; a wave covers 1 KiB contiguous).
// Full unroll -> 16 independent float4 loads in flight per wave (MLP).
__global__ __launch_bounds__(256, 8) void scores_partial_kernel(
    const float* __restrict__ q, const float* __restrict__ k,
    float* __restrict__ partial) {
  const int t    = blockIdx.x;
  const int n    = blockIdx.y;
  const int tid  = threadIdx.x;
  const int lane = tid & 63;
  const int wave = tid >> 6;       // 0..3
  const int sub  = lane >> 4;      // 0..3
  const int lq   = lane & 15;      // l-group
  const int g    = wave * 4 + sub; // 0..15

  __shared__ float ks[C];          // this block's k row, 1 KiB
  ks[tid] = k[t * (N * C) + n * C + tid];
  __syncthreads();

  const float* qnt = q + ((size_t)n * T + t) * (C * L);

  float4 acc = make_float4(0.f, 0.f, 0.f, 0.f);
  #pragma unroll
  for (int j = 0; j < 16; ++j) {   // c = g + 16j, fully unrolled
    const int c = g + j * 16;
    const float4 qv = *reinterpret_cast<const float4*>(qnt + (size_t)c * L + lq * 4);
    const float kv = ks[c];
    acc.x = fmaf(qv.x, kv, acc.x);
    acc.y = fmaf(qv.y, kv, acc.y);
    acc.z = fmaf(qv.z, kv, acc.z);
    acc.w = fmaf(qv.w, kv, acc.w);
  }

  // Sum the 4 quarter-waves of this wave (same l-groups, different c).
  acc.x += __shfl_xor(acc.x, 16); acc.y += __shfl_xor(acc.y, 16);
  acc.z += __shfl_xor(acc.z, 16); acc.w += __shfl_xor(acc.w, 16);
  acc.x += __shfl_xor(acc.x, 32); acc.y += __shfl_xor(acc.y, 32);
  acc.z += __shfl_xor(acc.z, 32); acc.w += __shfl_xor(acc.w, 32);

  // Cross-wave reduction via LDS (1 KiB).
  __shared__ float sdata[4 * L];
  if (lane < 16) {
    sdata[wave * L + lq * 4 + 0] = acc.x;
    sdata[wave * L + lq * 4 + 1] = acc.y;
    sdata[wave * L + lq * 4 + 2] = acc.z;
    sdata[wave * L + lq * 4 + 3] = acc.w;
  }
  __syncthreads();
  if (tid < L) {
    const float s = sdata[tid] + sdata[L + tid] + sdata[2 * L + tid] + sdata[3 * L + tid];
    partial[(size_t)t * (N * L) + n * L + tid] = s;  // deterministic, no atomics
  }
}

// Kernel 2: every block recomputes softmax(scores[n,:]) from the 64 partials
// (16 KiB, L2-hot; reduction split across 4 waves, 16 independent loads each),
// then computes out[t,n,c] = dot(q[n,t,c,:], probs[n,:]) re-streaming q
// (L3-resident from pass 1 — R5 profile showed FETCH ~4 MB, q stays cached).
__global__ __launch_bounds__(256, 8) void out_kernel(
    const float* __restrict__ q, const float* __restrict__ partial,
    float* __restrict__ out) {
  const int t    = blockIdx.x;
  const int n    = blockIdx.y;
  const int tid  = threadIdx.x;
  const int lane = tid & 63;
  const int wave = tid >> 6;

  __shared__ float sred[4 * L];
  __shared__ float probs[L];
  {
    // Wave w sums partial blocks b in [16w, 16w+16); lane = l index.
    float s = 0.f;
    #pragma unroll
    for (int j = 0; j < 16; ++j) {
      const int b = wave * 16 + j;
      s += partial[(size_t)b * (N * L) + n * L + lane];
    }
    sred[wave * L + lane] = s;
  }
  __syncthreads();
  if (tid < L) {  // exactly wave 0 finishes softmax for l = tid
    float s = sred[tid] + sred[L + tid] + sred[2 * L + tid] + sred[3 * L + tid];
    float m = s;
    #pragma unroll
    for (int off = 32; off > 0; off >>= 1) m = fmaxf(m, __shfl_xor(m, off));
    const float e = __expf(s - m);
    float sum = e;
    #pragma unroll
    for (int off = 32; off > 0; off >>= 1) sum += __shfl_xor(sum, off);
    probs[tid] = e / sum;
  }
  __syncthreads();

  const int sub = lane >> 4;
  const int lq  = lane & 15;
  const int g   = wave * 4 + sub;

  const float4 pv = *reinterpret_cast<const float4*>(&probs[lq * 4]);
  const float* qnt = q + ((size_t)n * T + t) * (C * L);

  #pragma unroll
  for (int j = 0; j < 16; ++j) {   // fully unrolled: 16 loads in flight
    const int c = g + j * 16;
    const float4 qv = *reinterpret_cast<const float4*>(qnt + (size_t)c * L + lq * 4);
    float d = qv.x * pv.x + qv.y * pv.y + qv.z * pv.z + qv.w * pv.w;
    // Reduce across the 16 lanes of the quarter-wave.
    d += __shfl_xor(d, 1);
    d += __shfl_xor(d, 2);
    d += __shfl_xor(d, 4);
    d += __shfl_xor(d, 8);
    if (lq == 0) {
      // The four lq==0 lanes of a wave write 4 consecutive floats; never re-read.
      __builtin_nontemporal_store(d, &out[t * (N * C) + n * C + c]);
    }
  }
}

extern "C" void kernel_launch(void* const* d_in, const int* in_sizes, int n_in,
                              void* d_out, int out_size, void* d_ws, size_t ws_size,
                              hipStream_t stream) {
  const float* q = (const float*)d_in[0];   // query: (32,64,256,64) fp32
  const float* k = (const float*)d_in[1];   // key:   (64,32,256)    fp32
  float* out = (float*)d_out;               // out:   (64,32,256)    fp32
  float* partial = (float*)d_ws;            // [64][32][64] fp32 = 512 KiB scratch

  dim3 grid(BLK_PER_N, N);                  // 2048 blocks x 256 threads = 8 blocks/CU
  scores_partial_kernel<<<grid, 256, 0, stream>>>(q, k, partial);
  out_kernel<<<grid, 256, 0, stream>>>(q, partial, out);
}